// Round 8
// baseline (894.213 us; speedup 1.0000x reference)
//
#include <hip/hip_runtime.h>

// TreecrfLossSRL: inside algorithm (logsumexp semiring), B=64, N=256.
// Two CYK charts per batch (ob / allv) -> scalar (logz - marg).sum()/denom.
//
// Width-major triangular chart in LDS, columns padded to x4 floats
// (cst4(v) closed form), values scaled by log2(e). The FULL D matrix is
// pre-filled into the chart (col w holds D(*,w) until level w finalizes
// in place). Lane covers WIDE adjacent entries:
//   left  = float4/float2 at Lc[cst4(u) + WIDE*lane]   (aligned, b128/b64)
//   right = Lc[cst4(w-u) + u + WIDE*lane + k]          (stride-1 b32)
// u-range split across 16 waves; per-(wave,entry) partial m+log2(s) in
// scr (b128 write); finalize adds pre-stored D and writes col w in place.

#define NN 256
#define BATCH 64
#define NCHART (2 * BATCH)
#define NEGV -1000000000.0f
#define NEGB -1.0e30f
#define K2f 1.4426950408889634f   /* log2(e) */
#define LN2f 0.6931471805599453f

#define CHARTF 33280                   /* triangular, cols padded to x4 */
#define SCR_OFF CHARTF                 /* 16 waves x 256 entries, f32 */
#define LDSF (CHARTF + 4096)           /* 37376 floats = 149504 B */

#define RES_OFF ((size_t)16)
#define LEN_OFF ((size_t)(16 + NCHART))
#define FB_OFF  ((size_t)(16 + NCHART + BATCH + 16))

__device__ __forceinline__ float fexp2(float x) {
#if __has_builtin(__builtin_amdgcn_exp2f)
    return __builtin_amdgcn_exp2f(x);
#else
    return exp2f(x);
#endif
}

// padded column start (floats) for width v, v in 1..256
__device__ __forceinline__ int cst4(int v) {
    int q = (v - 1) >> 2, r = (v - 1) & 3;
    return (q << 10) - ((q * (q - 1)) << 3) + r * (256 - (q << 2));
}

// natural-log score at span [i, j] for type t (0 = ob/constrained, 1 = allv)
__device__ __forceinline__ float score_at(const float* __restrict__ logits,
                                          const int* __restrict__ spans_ind,
                                          const void* __restrict__ span_mask,
                                          int isb, int t, int b, int i, int j) {
    size_t sidx = ((size_t)b * NN + i) * NN + j;
    float l0 = logits[2 * sidx];
    float l1 = logits[2 * sidx + 1];
    if (t) {
        float mx = fmaxf(l0, l1), mn = fminf(l0, l1);
        return mx + log1pf(__expf(mn - mx));
    } else {
        bool sind = (spans_ind[sidx] == 2);
        bool sm = isb ? (((const unsigned char*)span_mask)[sidx] != 0)
                      : (((const int*)span_mask)[sidx] != 0);
        float s0 = (sm || sind)  ? NEGV : l0;
        float s1 = (sm || !sind) ? NEGV : l1;
        float mx = fmaxf(s0, s1), mn = fminf(s0, s1);
        return mx + log1pf(__expf(mn - mx));
    }
}

// combine 16 wave partials (tree) + pre-stored D, write col w in place
__device__ __forceinline__ void finalize_level(
    float* __restrict__ Lc, const float* __restrict__ scr,
    int w, int E, int tid) {
    if (tid < E) {
        float p[16];
#pragma unroll
        for (int i = 0; i < 16; ++i) p[i] = scr[(i << 8) + tid];
        float m = fmaxf(
            fmaxf(fmaxf(fmaxf(p[0], p[1]), fmaxf(p[2], p[3])),
                  fmaxf(fmaxf(p[4], p[5]), fmaxf(p[6], p[7]))),
            fmaxf(fmaxf(fmaxf(p[8], p[9]), fmaxf(p[10], p[11])),
                  fmaxf(fmaxf(p[12], p[13]), fmaxf(p[14], p[15]))));
        float ss =
            ((fexp2(p[0] - m) + fexp2(p[1] - m)) +
             (fexp2(p[2] - m) + fexp2(p[3] - m))) +
            ((fexp2(p[4] - m) + fexp2(p[5] - m)) +
             (fexp2(p[6] - m) + fexp2(p[7] - m))) +
            ((fexp2(p[8] - m) + fexp2(p[9] - m)) +
             (fexp2(p[10] - m) + fexp2(p[11] - m))) +
            ((fexp2(p[12] - m) + fexp2(p[13] - m)) +
             (fexp2(p[14] - m) + fexp2(p[15] - m)));
        int a = cst4(w) + tid;
        Lc[a] = Lc[a] + m + __log2f(ss);   // D (pre-stored) + logsumexp
    }
}

// wide level: lane covers WIDE adjacent entries; left via b128/b64
template <int WIDE>
__device__ __forceinline__ void level_wide(
    float* __restrict__ Lc, float* __restrict__ scr,
    int w, int tid, int wave, int lane) {
    const int T = w - 1;
    const int E = NN + 1 - w;

    const int C = (T + 15) >> 4;
    const int u0 = 1 + wave * C;
    const int u1 = min(u0 + C, w);
    const int steps = u1 - u0;

    float M[WIDE], S[WIDE];
#pragma unroll
    for (int k = 0; k < WIDE; ++k) { M[k] = NEGB; S[k] = 0.f; }

    if (steps > 0) {
        int u = u0, v = w - u0;
        int la = cst4(u0) + WIDE * lane;
        int ra = cst4(v) + u0 + WIDE * lane;
        for (int it = steps >> 2; it > 0; --it) {
            const int la0 = la;
            const int la1 = la0 + ((260 - u) & ~3);
            const int la2 = la1 + ((259 - u) & ~3);
            const int la3 = la2 + ((258 - u) & ~3);
            la = la3 + ((257 - u) & ~3);
            const int ra0 = ra;
            const int ra1 = ra0 - ((261 - v) & ~3) + 1;
            const int ra2 = ra1 - ((262 - v) & ~3) + 1;
            const int ra3 = ra2 - ((263 - v) & ~3) + 1;
            ra = ra3 - ((264 - v) & ~3) + 1;
            float l0[WIDE], l1[WIDE], l2[WIDE], l3[WIDE];
            if constexpr (WIDE == 4) {
                *(float4*)l0 = *(const float4*)(Lc + la0);
                *(float4*)l1 = *(const float4*)(Lc + la1);
                *(float4*)l2 = *(const float4*)(Lc + la2);
                *(float4*)l3 = *(const float4*)(Lc + la3);
            } else {
                *(float2*)l0 = *(const float2*)(Lc + la0);
                *(float2*)l1 = *(const float2*)(Lc + la1);
                *(float2*)l2 = *(const float2*)(Lc + la2);
                *(float2*)l3 = *(const float2*)(Lc + la3);
            }
            float r0[WIDE], r1[WIDE], r2[WIDE], r3[WIDE];
#pragma unroll
            for (int k = 0; k < WIDE; ++k) {
                r0[k] = Lc[ra0 + k]; r1[k] = Lc[ra1 + k];
                r2[k] = Lc[ra2 + k]; r3[k] = Lc[ra3 + k];
            }
#pragma unroll
            for (int k = 0; k < WIDE; ++k) {
                float t0 = l0[k] + r0[k], t1 = l1[k] + r1[k];
                float t2 = l2[k] + r2[k], t3 = l3[k] + r3[k];
                float lm = fmaxf(fmaxf(t0, t1), fmaxf(t2, t3));
                float nm = fmaxf(M[k], lm);
                S[k] = S[k] * fexp2(M[k] - nm) +
                       ((fexp2(t0 - nm) + fexp2(t1 - nm)) +
                        (fexp2(t2 - nm) + fexp2(t3 - nm)));
                M[k] = nm;
            }
            u += 4; v -= 4;
        }
        for (int rem = steps & 3; rem > 0; --rem) {
            float l[WIDE], r[WIDE];
            if constexpr (WIDE == 4)
                *(float4*)l = *(const float4*)(Lc + la);
            else
                *(float2*)l = *(const float2*)(Lc + la);
#pragma unroll
            for (int k = 0; k < WIDE; ++k) r[k] = Lc[ra + k];
#pragma unroll
            for (int k = 0; k < WIDE; ++k) {
                float t0 = l[k] + r[k];
                float nm = fmaxf(M[k], t0);
                S[k] = S[k] * fexp2(M[k] - nm) + fexp2(t0 - nm);
                M[k] = nm;
            }
            la += (260 - u) & ~3;
            ra -= ((261 - v) & ~3) - 1;
            u += 1; v -= 1;
        }
    }

    // partial per (wave, entry): m + log2(s); vector write, slots >= E unread
    if (WIDE * lane < E) {
        float out[WIDE];
#pragma unroll
        for (int k = 0; k < WIDE; ++k) out[k] = M[k] + __log2f(S[k]);
        if constexpr (WIDE == 4)
            *(float4*)(scr + (wave << 8) + 4 * lane) = *(float4*)out;
        else
            *(float2*)(scr + (wave << 8) + 2 * lane) = *(float2*)out;
    }
    __syncthreads();
    finalize_level(Lc, scr, w, E, tid);
    __syncthreads();
}

// small-E path (w >= 193, E <= 64): sub-grouped u-split
__device__ __forceinline__ void level_small(
    float* __restrict__ Lc, float* __restrict__ scr,
    int w, int tid, int wave, int lane) {
    const int T = w - 1;
    const int E = NN + 1 - w;

    const int EH = (E <= 1) ? 1 : (1 << (32 - __clz(E - 1)));  // pow2 >= E
    const int sh2 = (EH == 1) ? 0 : (31 - __clz(EH));
    const int g = lane & (EH - 1);
    const int slot = (wave << (6 - sh2)) + (lane >> sh2);
    const int slots_sh = 10 - sh2;
    const int C = (T + (1 << slots_sh) - 1) >> slots_sh;
    const int u0 = 1 + slot * C;
    const int u1 = min(u0 + C, w);
    const int steps = u1 - u0;

    float M0 = NEGB, S0 = 0.f;
    if (steps > 0) {
        int u = u0, v = w - u0;
        int la = cst4(u0) + g;
        int ra = cst4(v) + g + u0;
        for (int it = steps; it > 0; --it) {
            float tv0 = Lc[la] + Lc[ra];
            float nm = fmaxf(M0, tv0);
            S0 = S0 * fexp2(M0 - nm) + fexp2(tv0 - nm);
            M0 = nm;
            la += (260 - u) & ~3;
            ra -= ((261 - v) & ~3) - 1;
            u += 1; v -= 1;
        }
    }
    for (int d = 32; d >= EH; d >>= 1) {
        float mm = __shfl_xor(M0, d);
        float ss = __shfl_xor(S0, d);
        float nm = fmaxf(M0, mm);
        S0 = S0 * fexp2(M0 - nm) + ss * fexp2(mm - nm);
        M0 = nm;
    }
    if ((lane >> sh2) == 0)
        scr[(wave << 8) + g] = M0 + __log2f(S0);
    __syncthreads();
    finalize_level(Lc, scr, w, E, tid);
    __syncthreads();
}

template <bool USE_LDS>
__global__ __launch_bounds__(1024) void cyk_kernel(
    const float* __restrict__ logits,     // [B,N,N,2] f32
    const int* __restrict__ spans_ind,    // [B,N,N] i32
    const void* __restrict__ maskspan,    // [B,N,N] bool (byte or i32)
    const void* __restrict__ span_mask,   // [B,N,N] bool
    float* __restrict__ ws) {
    extern __shared__ float lds[];
    const int c = blockIdx.x;
    const int b = c >> 1;
    const int t = c & 1;
    const int tid = threadIdx.x;
    const int wave = tid >> 6, lane = tid & 63;

    float* __restrict__ Lc = USE_LDS ? lds : (ws + FB_OFF + (size_t)c * LDSF);
    float* __restrict__ scr = Lc + SCR_OFF;

    __shared__ int s_len;
    __shared__ int s_isb;
    if (tid == 0) {
        s_len = 0;
        unsigned probe = *(const unsigned*)maskspan;
        s_isb = (probe > 1u) ? 1 : 0;  // byte-packed bools -> 0x01010101
    }
    __syncthreads();
    const int isb = s_isb;

    // lens[b] = sum_j maskspan[b,0,j]
    if (tid < NN) {
        size_t off = (size_t)b * NN * NN + tid;
        int v = isb ? (((const unsigned char*)maskspan)[off] ? 1 : 0)
                    : (((const int*)maskspan)[off] ? 1 : 0);
        atomicAdd(&s_len, v);
    }

    // one-time D-fill: chart col w holds K2f * D(i, w) until level w
    for (int it = 0; it < 64; ++it) {
        int f = (it << 10) + tid;            // over the (i, j) square
        int i = f >> 8, j = f & 255;
        if (j >= i) {
            float sc = score_at(logits, spans_ind, span_mask, isb, t, b, i, j);
            Lc[cst4(j - i + 1) + i] = K2f * sc;
        }
    }
    __syncthreads();

    for (int w = 2; w <= 128; ++w)
        level_wide<4>(Lc, scr, w, tid, wave, lane);
    for (int w = 129; w <= 192; ++w)
        level_wide<2>(Lc, scr, w, tid, wave, lane);
    for (int w = 193; w <= NN; ++w)
        level_small(Lc, scr, w, tid, wave, lane);

    if (tid == 0) {
        int len = s_len;
        float rres = (len >= 1) ? (Lc[cst4(len)] * LN2f) : NEGV;
        ws[RES_OFF + c] = rres;
        if (t == 0) ws[LEN_OFF + b] = (float)len;
    }
}

__global__ __launch_bounds__(64) void finish_kernel(const float* __restrict__ ws,
                                                    float* __restrict__ out) {
    int b = threadIdx.x;  // 0..63
    float diff = ws[RES_OFF + 2 * b + 1] - ws[RES_OFF + 2 * b];
    float len  = ws[LEN_OFF + b];
    for (int d = 32; d > 0; d >>= 1) {
        diff += __shfl_xor(diff, d);
        len  += __shfl_xor(len, d);
    }
    if (b == 0) out[0] = diff / len;
}

extern "C" void kernel_launch(void* const* d_in, const int* in_sizes, int n_in,
                              void* d_out, int out_size, void* d_ws, size_t ws_size,
                              hipStream_t stream) {
    const float* logits    = (const float*)d_in[0];
    const int*   spans_ind = (const int*)d_in[1];
    const void*  maskspan  = d_in[2];
    const void*  span_mask = d_in[3];
    float* ws = (float*)d_ws;

    const size_t shbytes = (size_t)LDSF * sizeof(float);  // 149504 B
    hipError_t e = hipFuncSetAttribute(
        reinterpret_cast<const void*>(&cyk_kernel<true>),
        hipFuncAttributeMaxDynamicSharedMemorySize, (int)shbytes);
    if (e == hipSuccess) {
        hipLaunchKernelGGL(cyk_kernel<true>, dim3(NCHART), dim3(1024), shbytes,
                           stream, logits, spans_ind, maskspan, span_mask, ws);
    } else {
        hipLaunchKernelGGL(cyk_kernel<false>, dim3(NCHART), dim3(1024), 0,
                           stream, logits, spans_ind, maskspan, span_mask, ws);
    }
    hipLaunchKernelGGL(finish_kernel, dim3(1), dim3(64), 0, stream,
                       ws, (float*)d_out);
}

// Round 9
// 608.404 us; speedup vs baseline: 1.4698x; 1.4698x over previous
//
#include <hip/hip_runtime.h>

// TreecrfLossSRL: inside algorithm (logsumexp semiring), B=64, N=256.
// Two CYK charts per batch (ob / allv) -> scalar (logz - marg).sum()/denom.
//
// Width-major triangular chart in LDS, NO padding (col v starts at
// cst(v) = 257(v-1) - v(v-1)/2), values scaled by log2(e).
// D-PREFILL: one coalesced pass writes K2f*D(i,j) into chart col (j-i+1);
// col w holds D until level w finalizes in place (A = D + LSE) -> no
// per-level global loads, no per-level libm.
// Level w, lane l accumulates entries g = l + 64k (k < KK, compile-time):
//   left  = Lc[cst(u)   + g]      stride-1 across lanes -> conflict-free
//   right = Lc[cst(w-u) + u + g]  stride-1 across lanes -> conflict-free
// u-range split across 16 waves; per-(wave,entry) partial m+log2(s) in
// transposed scratch; finalize = 16-way tree + pre-stored D, in place.

#define NN 256
#define BATCH 64
#define NCHART (2 * BATCH)
#define NEGV -1000000000.0f
#define NEGB -1.0e30f
#define K2f 1.4426950408889634f   /* log2(e) */
#define LN2f 0.6931471805599453f

#define CHARTF 32896                   /* triangular chart, no padding */
#define SCR_OFF CHARTF                 /* 16 waves x 256 entries, f32 */
#define LDSF (CHARTF + 4096)           /* 36992 floats = 147968 B */

#define RES_OFF ((size_t)16)
#define LEN_OFF ((size_t)(16 + NCHART))
#define FB_OFF  ((size_t)(16 + NCHART + BATCH + 16))

__device__ __forceinline__ float fexp2(float x) {
#if __has_builtin(__builtin_amdgcn_exp2f)
    return __builtin_amdgcn_exp2f(x);
#else
    return exp2f(x);
#endif
}

// column start (floats) for width v, v in 1..256
__device__ __forceinline__ int cstart(int v) {
    return 257 * (v - 1) - ((v * (v - 1)) >> 1);
}

// natural-log score at span [i, j] for type t (0 = ob/constrained, 1 = allv)
__device__ __forceinline__ float score_at(const float* __restrict__ logits,
                                          const int* __restrict__ spans_ind,
                                          const void* __restrict__ span_mask,
                                          int isb, int t, int b, int i, int j) {
    size_t sidx = ((size_t)b * NN + i) * NN + j;
    float l0 = logits[2 * sidx];
    float l1 = logits[2 * sidx + 1];
    if (t) {
        float mx = fmaxf(l0, l1), mn = fminf(l0, l1);
        return mx + log1pf(__expf(mn - mx));
    } else {
        bool sind = (spans_ind[sidx] == 2);
        bool sm = isb ? (((const unsigned char*)span_mask)[sidx] != 0)
                      : (((const int*)span_mask)[sidx] != 0);
        float s0 = (sm || sind)  ? NEGV : l0;
        float s1 = (sm || !sind) ? NEGV : l1;
        float mx = fmaxf(s0, s1), mn = fminf(s0, s1);
        return mx + log1pf(__expf(mn - mx));
    }
}

// combine 16 wave partials (tree) + pre-stored D, write col w in place
__device__ __forceinline__ void finalize_level(
    float* __restrict__ Lc, const float* __restrict__ scr,
    int w, int E, int tid) {
    if (tid < E) {
        float p[16];
#pragma unroll
        for (int i = 0; i < 16; ++i) p[i] = scr[(i << 8) + tid];
        float m = fmaxf(
            fmaxf(fmaxf(fmaxf(p[0], p[1]), fmaxf(p[2], p[3])),
                  fmaxf(fmaxf(p[4], p[5]), fmaxf(p[6], p[7]))),
            fmaxf(fmaxf(fmaxf(p[8], p[9]), fmaxf(p[10], p[11])),
                  fmaxf(fmaxf(p[12], p[13]), fmaxf(p[14], p[15]))));
        float ss =
            ((fexp2(p[0] - m) + fexp2(p[1] - m)) +
             (fexp2(p[2] - m) + fexp2(p[3] - m))) +
            ((fexp2(p[4] - m) + fexp2(p[5] - m)) +
             (fexp2(p[6] - m) + fexp2(p[7] - m))) +
            ((fexp2(p[8] - m) + fexp2(p[9] - m)) +
             (fexp2(p[10] - m) + fexp2(p[11] - m))) +
            ((fexp2(p[12] - m) + fexp2(p[13] - m)) +
             (fexp2(p[14] - m) + fexp2(p[15] - m)));
        int a = cstart(w) + tid;
        Lc[a] = Lc[a] + m + __log2f(ss);   // D (pre-stored) + logsumexp
    }
}

// one level with compile-time KK (entries per lane)
template <int KK>
__device__ __forceinline__ void level_kk(
    float* __restrict__ Lc, float* __restrict__ scr,
    int w, int tid, int wave, int lane) {
    const int T = w - 1;
    const int E = NN + 1 - w;

    const int C = (T + 15) >> 4;
    const int u0 = 1 + wave * C;
    const int u1 = min(u0 + C, w);
    const int steps = u1 - u0;

    float M[KK], S[KK];
#pragma unroll
    for (int k = 0; k < KK; ++k) { M[k] = NEGB; S[k] = 0.f; }

    if (steps > 0) {
        const int v0 = w - u0;
        int la = cstart(u0) + lane;
        int ra = cstart(v0) + u0 + lane;
        int A = 257 - u0;
        int B = 257 - v0;
        for (int it = steps >> 2; it > 0; --it) {
            const int la1 = la + A, la2 = la1 + A - 1, la3 = la2 + A - 2;
            const int ra1 = ra - B, ra2 = ra1 - B - 1, ra3 = ra2 - B - 2;
            float tv[KK][4];
#pragma unroll
            for (int k = 0; k < KK; ++k) {
                float lx0 = Lc[la  + 64 * k], lx1 = Lc[la1 + 64 * k];
                float lx2 = Lc[la2 + 64 * k], lx3 = Lc[la3 + 64 * k];
                float rx0 = Lc[ra  + 64 * k], rx1 = Lc[ra1 + 64 * k];
                float rx2 = Lc[ra2 + 64 * k], rx3 = Lc[ra3 + 64 * k];
                tv[k][0] = lx0 + rx0; tv[k][1] = lx1 + rx1;
                tv[k][2] = lx2 + rx2; tv[k][3] = lx3 + rx3;
            }
#pragma unroll
            for (int k = 0; k < KK; ++k) {
                float lm = fmaxf(fmaxf(tv[k][0], tv[k][1]),
                                 fmaxf(tv[k][2], tv[k][3]));
                float nm = fmaxf(M[k], lm);
                float e0 = fexp2(tv[k][0] - nm), e1 = fexp2(tv[k][1] - nm);
                float e2 = fexp2(tv[k][2] - nm), e3 = fexp2(tv[k][3] - nm);
                S[k] = S[k] * fexp2(M[k] - nm) + ((e0 + e1) + (e2 + e3));
                M[k] = nm;
            }
            la += 4 * A - 6; A -= 4;
            ra -= 4 * B + 6; B += 4;
        }
        for (int rem = steps & 3; rem > 0; --rem) {
#pragma unroll
            for (int k = 0; k < KK; ++k) {
                float tv0 = Lc[la + 64 * k] + Lc[ra + 64 * k];
                float nm = fmaxf(M[k], tv0);
                S[k] = S[k] * fexp2(M[k] - nm) + fexp2(tv0 - nm);
                M[k] = nm;
            }
            la += A; A -= 1;
            ra -= B; B += 1;
        }
    }

    // compressed partial per (wave, entry): m + log2(s)  [stride-1, masked]
#pragma unroll
    for (int k = 0; k < KK; ++k) {
        int g = lane + 64 * k;
        if (g < E) scr[(wave << 8) + g] = M[k] + __log2f(S[k]);
    }
    __syncthreads();
    finalize_level(Lc, scr, w, E, tid);
    __syncthreads();
}

// small-E path (w >= 193, E <= 64): sub-grouped u-split
__device__ __forceinline__ void level_small(
    float* __restrict__ Lc, float* __restrict__ scr,
    int w, int tid, int wave, int lane) {
    const int T = w - 1;
    const int E = NN + 1 - w;

    const int EH = (E <= 1) ? 1 : (1 << (32 - __clz(E - 1)));  // pow2 >= E
    const int sh2 = (EH == 1) ? 0 : (31 - __clz(EH));
    const int g = lane & (EH - 1);
    const int slot = (wave << (6 - sh2)) + (lane >> sh2);
    const int slots_sh = 10 - sh2;
    const int C = (T + (1 << slots_sh) - 1) >> slots_sh;
    const int u0 = 1 + slot * C;
    const int u1 = min(u0 + C, w);
    const int steps = u1 - u0;

    float M0 = NEGB, S0 = 0.f;
    if (steps > 0) {
        const int v0 = w - u0;
        int la = cstart(u0) + g;
        int ra = cstart(v0) + g + u0;
        int A = 257 - u0;
        int B = 257 - v0;
        for (int it = steps; it > 0; --it) {
            float tv0 = Lc[la] + Lc[ra];
            float nm = fmaxf(M0, tv0);
            S0 = S0 * fexp2(M0 - nm) + fexp2(tv0 - nm);
            M0 = nm;
            la += A; A -= 1;
            ra -= B; B += 1;
        }
    }
    for (int d = 32; d >= EH; d >>= 1) {
        float mm = __shfl_xor(M0, d);
        float ss = __shfl_xor(S0, d);
        float nm = fmaxf(M0, mm);
        S0 = S0 * fexp2(M0 - nm) + ss * fexp2(mm - nm);
        M0 = nm;
    }
    if ((lane >> sh2) == 0)
        scr[(wave << 8) + g] = M0 + __log2f(S0);
    __syncthreads();
    finalize_level(Lc, scr, w, E, tid);
    __syncthreads();
}

template <bool USE_LDS>
__global__ __launch_bounds__(1024) void cyk_kernel(
    const float* __restrict__ logits,     // [B,N,N,2] f32
    const int* __restrict__ spans_ind,    // [B,N,N] i32
    const void* __restrict__ maskspan,    // [B,N,N] bool (byte or i32)
    const void* __restrict__ span_mask,   // [B,N,N] bool
    float* __restrict__ ws) {
    extern __shared__ float lds[];
    const int c = blockIdx.x;
    const int b = c >> 1;
    const int t = c & 1;
    const int tid = threadIdx.x;
    const int wave = tid >> 6, lane = tid & 63;

    float* __restrict__ Lc = USE_LDS ? lds : (ws + FB_OFF + (size_t)c * LDSF);
    float* __restrict__ scr = Lc + SCR_OFF;

    __shared__ int s_len;
    __shared__ int s_isb;
    if (tid == 0) {
        s_len = 0;
        unsigned probe = *(const unsigned*)maskspan;
        s_isb = (probe > 1u) ? 1 : 0;  // byte-packed bools -> 0x01010101
    }
    __syncthreads();
    const int isb = s_isb;

    // lens[b] = sum_j maskspan[b,0,j]
    if (tid < NN) {
        size_t off = (size_t)b * NN * NN + tid;
        int v = isb ? (((const unsigned char*)maskspan)[off] ? 1 : 0)
                    : (((const int*)maskspan)[off] ? 1 : 0);
        atomicAdd(&s_len, v);
    }

    // one-time D-fill: chart col v = j-i+1 holds K2f * D(i, v) until level v
    for (int it = 0; it < 64; ++it) {
        int f = (it << 10) + tid;            // over the (i, j) square
        int i = f >> 8, j = f & 255;
        if (j >= i) {
            float sc = score_at(logits, spans_ind, span_mask, isb, t, b, i, j);
            Lc[cstart(j - i + 1) + i] = K2f * sc;
        }
    }
    __syncthreads();

    for (int w = 2; w <= 64; ++w)
        level_kk<4>(Lc, scr, w, tid, wave, lane);
    for (int w = 65; w <= 128; ++w)
        level_kk<3>(Lc, scr, w, tid, wave, lane);
    for (int w = 129; w <= 192; ++w)
        level_kk<2>(Lc, scr, w, tid, wave, lane);
    for (int w = 193; w <= NN; ++w)
        level_small(Lc, scr, w, tid, wave, lane);

    if (tid == 0) {
        int len = s_len;
        float rres = (len >= 1) ? (Lc[cstart(len)] * LN2f) : NEGV;
        ws[RES_OFF + c] = rres;
        if (t == 0) ws[LEN_OFF + b] = (float)len;
    }
}

__global__ __launch_bounds__(64) void finish_kernel(const float* __restrict__ ws,
                                                    float* __restrict__ out) {
    int b = threadIdx.x;  // 0..63
    float diff = ws[RES_OFF + 2 * b + 1] - ws[RES_OFF + 2 * b];
    float len  = ws[LEN_OFF + b];
    for (int d = 32; d > 0; d >>= 1) {
        diff += __shfl_xor(diff, d);
        len  += __shfl_xor(len, d);
    }
    if (b == 0) out[0] = diff / len;
}

extern "C" void kernel_launch(void* const* d_in, const int* in_sizes, int n_in,
                              void* d_out, int out_size, void* d_ws, size_t ws_size,
                              hipStream_t stream) {
    const float* logits    = (const float*)d_in[0];
    const int*   spans_ind = (const int*)d_in[1];
    const void*  maskspan  = d_in[2];
    const void*  span_mask = d_in[3];
    float* ws = (float*)d_ws;

    const size_t shbytes = (size_t)LDSF * sizeof(float);  // 147968 B
    hipError_t e = hipFuncSetAttribute(
        reinterpret_cast<const void*>(&cyk_kernel<true>),
        hipFuncAttributeMaxDynamicSharedMemorySize, (int)shbytes);
    if (e == hipSuccess) {
        hipLaunchKernelGGL(cyk_kernel<true>, dim3(NCHART), dim3(1024), shbytes,
                           stream, logits, spans_ind, maskspan, span_mask, ws);
    } else {
        hipLaunchKernelGGL(cyk_kernel<false>, dim3(NCHART), dim3(1024), 0,
                           stream, logits, spans_ind, maskspan, span_mask, ws);
    }
    hipLaunchKernelGGL(finish_kernel, dim3(1), dim3(64), 0, stream,
                       ws, (float*)d_out);
}

// Round 10
// 573.845 us; speedup vs baseline: 1.5583x; 1.0602x over previous
//
#include <hip/hip_runtime.h>

// TreecrfLossSRL: inside algorithm (logsumexp semiring), B=64, N=256.
// Two CYK charts per batch (ob / allv) -> scalar (logz - marg).sum()/denom.
//
// Width-major triangular chart in LDS (col v starts at cst(v)), log2-scaled,
// D prefilled in place (col w holds D until level w finalizes in place).
// PAIRED LEVELS (w, w+1): left operand Lc[cst(u)+g] is shared by both levels
// -> 3 LDS reads per u-term-pair instead of 4; 3 barriers per 2 levels.
// Level w+1's u=1 and u=w terms (need col w) are folded into its finalize.
// All chart/scr accesses stride-1 across lanes (conflict-free, r6-proven).
// Levels 2..5 use a trivial direct path (frees scr space: LDS = 163,648 B).

#define NN 256
#define BATCH 64
#define NCHART (2 * BATCH)
#define NEGV -1000000000.0f
#define NEGB -1.0e30f
#define K2f 1.4426950408889634f   /* log2(e) */
#define LN2f 0.6931471805599453f

#define CHARTF 32896                   /* triangular chart, no padding */
#define SCR_OFF CHARTF
#define SCRF 8016                      /* 16*(E0+E1) max at w=6 */
#define LDSF (CHARTF + SCRF)           /* 40912 floats = 163648 B */

#define RES_OFF ((size_t)16)
#define LEN_OFF ((size_t)(16 + NCHART))
#define FB_OFF  ((size_t)(16 + NCHART + BATCH + 16))

__device__ __forceinline__ float fexp2(float x) {
#if __has_builtin(__builtin_amdgcn_exp2f)
    return __builtin_amdgcn_exp2f(x);
#else
    return exp2f(x);
#endif
}

// column start (floats) for width v, v in 1..256
__device__ __forceinline__ int cstart(int v) {
    return 257 * (v - 1) - ((v * (v - 1)) >> 1);
}

#define ONLINE1(M, S, T0)                                   \
    {                                                       \
        float nm_ = fmaxf(M, T0);                           \
        S = S * fexp2(M - nm_) + fexp2(T0 - nm_);           \
        M = nm_;                                            \
    }

#define ONLINE4(M, S, t0, t1, t2, t3)                       \
    {                                                       \
        float lm_ = fmaxf(fmaxf(t0, t1), fmaxf(t2, t3));    \
        float nm_ = fmaxf(M, lm_);                          \
        S = S * fexp2(M - nm_) +                            \
            ((fexp2(t0 - nm_) + fexp2(t1 - nm_)) +          \
             (fexp2(t2 - nm_) + fexp2(t3 - nm_)));          \
        M = nm_;                                            \
    }

// natural-log score at span [i, j] for type t (0 = ob/constrained, 1 = allv)
__device__ __forceinline__ float score_at(const float* __restrict__ logits,
                                          const int* __restrict__ spans_ind,
                                          const void* __restrict__ span_mask,
                                          int isb, int t, int b, int i, int j) {
    size_t sidx = ((size_t)b * NN + i) * NN + j;
    float l0 = logits[2 * sidx];
    float l1 = logits[2 * sidx + 1];
    if (t) {
        float mx = fmaxf(l0, l1), mn = fminf(l0, l1);
        return mx + log1pf(__expf(mn - mx));
    } else {
        bool sind = (spans_ind[sidx] == 2);
        bool sm = isb ? (((const unsigned char*)span_mask)[sidx] != 0)
                      : (((const int*)span_mask)[sidx] != 0);
        float s0 = (sm || sind)  ? NEGV : l0;
        float s1 = (sm || !sind) ? NEGV : l1;
        float mx = fmaxf(s0, s1), mn = fminf(s0, s1);
        return mx + log1pf(__expf(mn - mx));
    }
}

__device__ __forceinline__ float tree16_max(const float* p) {
    return fmaxf(
        fmaxf(fmaxf(fmaxf(p[0], p[1]), fmaxf(p[2], p[3])),
              fmaxf(fmaxf(p[4], p[5]), fmaxf(p[6], p[7]))),
        fmaxf(fmaxf(fmaxf(p[8], p[9]), fmaxf(p[10], p[11])),
              fmaxf(fmaxf(p[12], p[13]), fmaxf(p[14], p[15]))));
}
__device__ __forceinline__ float tree16_sum(const float* p, float m) {
    return ((fexp2(p[0] - m) + fexp2(p[1] - m)) +
            (fexp2(p[2] - m) + fexp2(p[3] - m))) +
           ((fexp2(p[4] - m) + fexp2(p[5] - m)) +
            (fexp2(p[6] - m) + fexp2(p[7] - m))) +
           ((fexp2(p[8] - m) + fexp2(p[9] - m)) +
            (fexp2(p[10] - m) + fexp2(p[11] - m))) +
           ((fexp2(p[12] - m) + fexp2(p[13] - m)) +
            (fexp2(p[14] - m) + fexp2(p[15] - m)));
}

// combine 16 wave partials (stride-strided scr) + pre-stored D, in place
__device__ __forceinline__ void finalize_lo(
    float* __restrict__ Lc, const float* __restrict__ scrR,
    int stride, int w, int E, int tid) {
    if (tid < E) {
        float p[16];
#pragma unroll
        for (int i = 0; i < 16; ++i) p[i] = scrR[i * stride + tid];
        float m = tree16_max(p);
        float ss = tree16_sum(p, m);
        int a = cstart(w) + tid;
        Lc[a] = Lc[a] + m + __log2f(ss);
    }
}

// level w+1 finalize: 16 partials + terms u=1 and u=w (need col w) + D
__device__ __forceinline__ void finalize_hi(
    float* __restrict__ Lc, const float* __restrict__ scr1,
    int w1, int E1, int tid) {
    if (tid < E1) {
        float p[16];
#pragma unroll
        for (int i = 0; i < 16; ++i) p[i] = scr1[i * E1 + tid];
        int cw = cstart(w1 - 1);
        float ta = Lc[tid] + Lc[cw + tid + 1];          // u = 1
        float tb = Lc[cw + tid] + Lc[tid + (w1 - 1)];   // u = w
        float m = fmaxf(tree16_max(p), fmaxf(ta, tb));
        float ss = tree16_sum(p, m) + fexp2(ta - m) + fexp2(tb - m);
        int a = cstart(w1) + tid;
        Lc[a] = Lc[a] + m + __log2f(ss);
    }
}

// paired levels (w, w+1), compile-time KK = ceil(E0/64)
template <int KK>
__device__ __forceinline__ void level_pair(
    float* __restrict__ Lc, float* __restrict__ scr,
    int w, int tid, int wave, int lane) {
    const int T = w - 1;
    const int E0 = NN + 1 - w;
    const int E1 = NN - w;
    float* __restrict__ scr0 = scr;
    float* __restrict__ scr1 = scr + 16 * E0;

    const int C = (T + 15) >> 4;
    const int u0 = 1 + wave * C;
    const int u1 = min(u0 + C, w);
    int steps = u1 - u0;

    float M0[KK], S0[KK], M1[KK], S1[KK];
#pragma unroll
    for (int k = 0; k < KK; ++k) {
        M0[k] = NEGB; S0[k] = 0.f; M1[k] = NEGB; S1[k] = 0.f;
    }

    if (steps > 0) {
        int u = u0, v = w - u0;
        int la  = cstart(u) + lane;
        int ra0 = cstart(v) + u + lane;
        int ra1 = cstart(v + 1) + u + lane;
        int A = 257 - u;   // la stride (decrementing per u)
        int B = 257 - v;   // ra0 stride (incrementing per u)

        if (u == 1) {      // level-w-only term at u = 1 (wave 0 only)
#pragma unroll
            for (int k = 0; k < KK; ++k) {
                float tv0 = Lc[la + 64 * k] + Lc[ra0 + 64 * k];
                ONLINE1(M0[k], S0[k], tv0);
            }
            la += A; A -= 1;
            ra0 -= B; ra1 -= B - 1; B += 1;
            ++u; --steps;
        }

        for (int it = steps >> 2; it > 0; --it) {
            const int la1 = la + A, la2 = la1 + A - 1, la3 = la2 + A - 2;
            const int rb0 = ra0 - B, rc0 = rb0 - B - 1, rd0 = rc0 - B - 2;
            const int rb1 = ra1 - (B - 1), rc1 = rb1 - B, rd1 = rc1 - B - 1;
            float l[KK][4], r0[KK][4], r1[KK][4];
#pragma unroll
            for (int k = 0; k < KK; ++k) {
                l[k][0] = Lc[la  + 64 * k]; l[k][1] = Lc[la1 + 64 * k];
                l[k][2] = Lc[la2 + 64 * k]; l[k][3] = Lc[la3 + 64 * k];
                r0[k][0] = Lc[ra0 + 64 * k]; r0[k][1] = Lc[rb0 + 64 * k];
                r0[k][2] = Lc[rc0 + 64 * k]; r0[k][3] = Lc[rd0 + 64 * k];
                r1[k][0] = Lc[ra1 + 64 * k]; r1[k][1] = Lc[rb1 + 64 * k];
                r1[k][2] = Lc[rc1 + 64 * k]; r1[k][3] = Lc[rd1 + 64 * k];
            }
#pragma unroll
            for (int k = 0; k < KK; ++k) {
                float a0 = l[k][0] + r0[k][0], a1 = l[k][1] + r0[k][1];
                float a2 = l[k][2] + r0[k][2], a3 = l[k][3] + r0[k][3];
                ONLINE4(M0[k], S0[k], a0, a1, a2, a3);
                float b0 = l[k][0] + r1[k][0], b1 = l[k][1] + r1[k][1];
                float b2 = l[k][2] + r1[k][2], b3 = l[k][3] + r1[k][3];
                ONLINE4(M1[k], S1[k], b0, b1, b2, b3);
            }
            la = la3 + (A - 3); A -= 4;
            ra0 = rd0 - (B + 3);
            ra1 = rd1 - (B + 2); B += 4;
            u += 4;
        }
        for (int rem = steps & 3; rem > 0; --rem) {
#pragma unroll
            for (int k = 0; k < KK; ++k) {
                float lv  = Lc[la + 64 * k];
                float rv0 = Lc[ra0 + 64 * k];
                float rv1 = Lc[ra1 + 64 * k];
                float ta = lv + rv0;
                ONLINE1(M0[k], S0[k], ta);
                float tb = lv + rv1;
                ONLINE1(M1[k], S1[k], tb);
            }
            la += A; A -= 1;
            ra0 -= B; ra1 -= B - 1; B += 1;
        }
    }

    // partials: m + log2(s), stride-1 across lanes, masked by E
#pragma unroll
    for (int k = 0; k < KK; ++k) {
        int g = lane + 64 * k;
        if (g < E0) scr0[wave * E0 + g] = M0[k] + __log2f(S0[k]);
        if (g < E1) scr1[wave * E1 + g] = M1[k] + __log2f(S1[k]);
    }
    __syncthreads();
    finalize_lo(Lc, scr0, E0, w, E0, tid);
    __syncthreads();
    finalize_hi(Lc, scr1, w + 1, E1, tid);
    __syncthreads();
}

// small-E path (w >= 194, E <= 63): sub-grouped u-split (r9-proven)
__device__ __forceinline__ void level_small(
    float* __restrict__ Lc, float* __restrict__ scr,
    int w, int tid, int wave, int lane) {
    const int T = w - 1;
    const int E = NN + 1 - w;

    const int EH = (E <= 1) ? 1 : (1 << (32 - __clz(E - 1)));  // pow2 >= E
    const int sh2 = (EH == 1) ? 0 : (31 - __clz(EH));
    const int g = lane & (EH - 1);
    const int slot = (wave << (6 - sh2)) + (lane >> sh2);
    const int slots_sh = 10 - sh2;
    const int C = (T + (1 << slots_sh) - 1) >> slots_sh;
    const int u0 = 1 + slot * C;
    const int u1 = min(u0 + C, w);
    const int steps = u1 - u0;

    float M0 = NEGB, S0 = 0.f;
    if (steps > 0) {
        const int v0 = w - u0;
        int la = cstart(u0) + g;
        int ra = cstart(v0) + g + u0;
        int A = 257 - u0;
        int B = 257 - v0;
        for (int it = steps; it > 0; --it) {
            float tv0 = Lc[la] + Lc[ra];
            ONLINE1(M0, S0, tv0);
            la += A; A -= 1;
            ra -= B; B += 1;
        }
    }
    for (int d = 32; d >= EH; d >>= 1) {
        float mm = __shfl_xor(M0, d);
        float ss = __shfl_xor(S0, d);
        float nm = fmaxf(M0, mm);
        S0 = S0 * fexp2(M0 - nm) + ss * fexp2(mm - nm);
        M0 = nm;
    }
    if ((lane >> sh2) == 0)
        scr[(wave << 8) + g] = M0 + __log2f(S0);
    __syncthreads();
    finalize_lo(Lc, scr, 256, w, E, tid);
    __syncthreads();
}

// direct path for w in [2,5]: each thread does its entry's full LSE
__device__ __forceinline__ void level_direct(
    float* __restrict__ Lc, int w, int tid) {
    const int E = NN + 1 - w;
    if (tid < E) {
        float m = NEGB, s = 0.f;
        for (int u = 1; u <= w - 1; ++u) {
            float tv = Lc[cstart(u) + tid] + Lc[cstart(w - u) + u + tid];
            ONLINE1(m, s, tv);
        }
        int a = cstart(w) + tid;
        Lc[a] = Lc[a] + m + __log2f(s);
    }
    __syncthreads();
}

template <bool USE_LDS>
__global__ __launch_bounds__(1024) void cyk_kernel(
    const float* __restrict__ logits,     // [B,N,N,2] f32
    const int* __restrict__ spans_ind,    // [B,N,N] i32
    const void* __restrict__ maskspan,    // [B,N,N] bool (byte or i32)
    const void* __restrict__ span_mask,   // [B,N,N] bool
    float* __restrict__ ws) {
    extern __shared__ float lds[];
    const int c = blockIdx.x;
    const int b = c >> 1;
    const int t = c & 1;
    const int tid = threadIdx.x;
    const int wave = tid >> 6, lane = tid & 63;

    float* __restrict__ Lc = USE_LDS ? lds : (ws + FB_OFF + (size_t)c * LDSF);
    float* __restrict__ scr = Lc + SCR_OFF;

    __shared__ int s_len;
    __shared__ int s_isb;
    if (tid == 0) {
        s_len = 0;
        unsigned probe = *(const unsigned*)maskspan;
        s_isb = (probe > 1u) ? 1 : 0;  // byte-packed bools -> 0x01010101
    }
    __syncthreads();
    const int isb = s_isb;

    // lens[b] = sum_j maskspan[b,0,j]
    if (tid < NN) {
        size_t off = (size_t)b * NN * NN + tid;
        int v = isb ? (((const unsigned char*)maskspan)[off] ? 1 : 0)
                    : (((const int*)maskspan)[off] ? 1 : 0);
        atomicAdd(&s_len, v);
    }

    // one-time D-fill: chart col v = j-i+1 holds K2f * D(i, v) until level v
    for (int it = 0; it < 64; ++it) {
        int f = (it << 10) + tid;            // over the (i, j) square
        int i = f >> 8, j = f & 255;
        if (j >= i) {
            float sc = score_at(logits, spans_ind, span_mask, isb, t, b, i, j);
            Lc[cstart(j - i + 1) + i] = K2f * sc;
        }
    }
    __syncthreads();

    for (int w = 2; w <= 5; ++w)
        level_direct(Lc, w, tid);
    for (int w = 6; w <= 64; w += 2)
        level_pair<4>(Lc, scr, w, tid, wave, lane);
    for (int w = 66; w <= 128; w += 2)
        level_pair<3>(Lc, scr, w, tid, wave, lane);
    for (int w = 130; w <= 192; w += 2)
        level_pair<2>(Lc, scr, w, tid, wave, lane);
    for (int w = 194; w <= NN; ++w)
        level_small(Lc, scr, w, tid, wave, lane);

    if (tid == 0) {
        int len = s_len;
        float rres = (len >= 1) ? (Lc[cstart(len)] * LN2f) : NEGV;
        ws[RES_OFF + c] = rres;
        if (t == 0) ws[LEN_OFF + b] = (float)len;
    }
}

__global__ __launch_bounds__(64) void finish_kernel(const float* __restrict__ ws,
                                                    float* __restrict__ out) {
    int b = threadIdx.x;  // 0..63
    float diff = ws[RES_OFF + 2 * b + 1] - ws[RES_OFF + 2 * b];
    float len  = ws[LEN_OFF + b];
    for (int d = 32; d > 0; d >>= 1) {
        diff += __shfl_xor(diff, d);
        len  += __shfl_xor(len, d);
    }
    if (b == 0) out[0] = diff / len;
}

extern "C" void kernel_launch(void* const* d_in, const int* in_sizes, int n_in,
                              void* d_out, int out_size, void* d_ws, size_t ws_size,
                              hipStream_t stream) {
    const float* logits    = (const float*)d_in[0];
    const int*   spans_ind = (const int*)d_in[1];
    const void*  maskspan  = d_in[2];
    const void*  span_mask = d_in[3];
    float* ws = (float*)d_ws;

    const size_t shbytes = (size_t)LDSF * sizeof(float);  // 163648 B
    hipError_t e = hipFuncSetAttribute(
        reinterpret_cast<const void*>(&cyk_kernel<true>),
        hipFuncAttributeMaxDynamicSharedMemorySize, (int)shbytes);
    if (e == hipSuccess) {
        hipLaunchKernelGGL(cyk_kernel<true>, dim3(NCHART), dim3(1024), shbytes,
                           stream, logits, spans_ind, maskspan, span_mask, ws);
    } else {
        hipLaunchKernelGGL(cyk_kernel<false>, dim3(NCHART), dim3(1024), 0,
                           stream, logits, spans_ind, maskspan, span_mask, ws);
    }
    hipLaunchKernelGGL(finish_kernel, dim3(1), dim3(64), 0, stream,
                       ws, (float*)d_out);
}